// Round 6
// baseline (169.797 us; speedup 1.0000x reference)
//
#include <hip/hip_runtime.h>

#define N_NODES 100000
#define N_EDGES 6400000
#define RANGES 4
#define RANGE_S 25000     // nodes per range
#define NSUB 128          // sub-buckets per range (contention spreading)
#define CAP 13568         // records per sub-bucket; expected 12500, +11 sigma
#define P1_BLOCKS 2048
#define P1_THREADS 256

// ============ fallback path A: direct device atomics ============
__global__ void zero_out_kernel(float* __restrict__ out, int n) {
    int i = blockIdx.x * blockDim.x + threadIdx.x;
    if (i < n) out[i] = 0.0f;
}

__global__ void __launch_bounds__(256) scatter_direct_kernel(
        const float* __restrict__ x, const int* __restrict__ ei,
        const float* __restrict__ w, float* __restrict__ out) {
    int t = blockIdx.x * blockDim.x + threadIdx.x;
    int e0 = t * 4;
    if (e0 >= N_EDGES) return;
    int4   s4 = *reinterpret_cast<const int4*>(ei + e0);
    int4   d4 = *reinterpret_cast<const int4*>(ei + N_EDGES + e0);
    float4 w4 = *reinterpret_cast<const float4*>(w + e0);
    atomicAdd(&out[s4.x], w4.x * x[d4.x]);
    atomicAdd(&out[s4.y], w4.y * x[d4.y]);
    atomicAdd(&out[s4.z], w4.z * x[d4.z]);
    atomicAdd(&out[s4.w], w4.w * x[d4.w]);
}

// ============ fallback path B: R5 one-pass range kernel ============
#define NB 64
#define BLK 1024
__global__ void __launch_bounds__(BLK) scatter_range_kernel(
        const float* __restrict__ x, const int* __restrict__ ei,
        const float* __restrict__ w, float* __restrict__ partial) {
    __shared__ float bins[RANGE_S];
    const int r = blockIdx.x & (RANGES - 1);
    const int c = blockIdx.x >> 2;
    for (int i = threadIdx.x; i < RANGE_S; i += BLK) bins[i] = 0.0f;
    __syncthreads();
    const int chunk = N_EDGES / NB;
    const int base  = c * chunk;
    const int end   = base + chunk;
    const int lo    = r * RANGE_S;
    for (int e = base + (int)threadIdx.x * 8; e < end; e += BLK * 8) {
        int4   sa = *reinterpret_cast<const int4*>(ei + e);
        int4   sb = *reinterpret_cast<const int4*>(ei + e + 4);
        int4   da = *reinterpret_cast<const int4*>(ei + N_EDGES + e);
        int4   db = *reinterpret_cast<const int4*>(ei + N_EDGES + e + 4);
        float4 wa = *reinterpret_cast<const float4*>(w + e);
        float4 wb = *reinterpret_cast<const float4*>(w + e + 4);
        unsigned a[8] = {(unsigned)(sa.x-lo),(unsigned)(sa.y-lo),(unsigned)(sa.z-lo),(unsigned)(sa.w-lo),
                         (unsigned)(sb.x-lo),(unsigned)(sb.y-lo),(unsigned)(sb.z-lo),(unsigned)(sb.w-lo)};
        int d[8] = {da.x,da.y,da.z,da.w,db.x,db.y,db.z,db.w};
        float ww[8] = {wa.x,wa.y,wa.z,wa.w,wb.x,wb.y,wb.z,wb.w};
        float xv[8];
        #pragma unroll
        for (int k = 0; k < 8; ++k) { int gi = (a[k] < RANGE_S) ? d[k] : 0; xv[k] = x[gi]; }
        #pragma unroll
        for (int k = 0; k < 8; ++k) asm volatile("" : "+v"(xv[k]));
        #pragma unroll
        for (int k = 0; k < 8; ++k) if (a[k] < RANGE_S) atomicAdd(&bins[a[k]], ww[k] * xv[k]);
    }
    __syncthreads();
    float* outp = partial + (size_t)(r * NB + c) * RANGE_S;
    for (int i = threadIdx.x; i < RANGE_S; i += BLK) outp[i] = bins[i];
}

__global__ void reduce_range_kernel(const float* __restrict__ partial, float* __restrict__ out) {
    int i = blockIdx.x * blockDim.x + threadIdx.x;
    int n0 = i * 4;
    if (n0 >= N_NODES) return;
    int r = n0 / RANGE_S;
    int s = n0 - r * RANGE_S;
    const float* base = partial + (size_t)(r * NB) * RANGE_S + s;
    float4 acc = make_float4(0.f,0.f,0.f,0.f);
    for (int j = 0; j < NB; ++j) {
        float4 v = *reinterpret_cast<const float4*>(base + (size_t)j * RANGE_S);
        acc.x += v.x; acc.y += v.y; acc.z += v.z; acc.w += v.w;
    }
    *reinterpret_cast<float4*>(out + n0) = acc;
}

// ============ main path: two-phase bucketed scatter ============
__device__ __forceinline__ unsigned bf16_rne(float f) {
    unsigned b = __float_as_uint(f);
    b += 0x7FFFu + ((b >> 16) & 1u);
    return b >> 16;
}

__global__ void zero_cnt_kernel(unsigned* __restrict__ cnt) {
    int i = blockIdx.x * blockDim.x + threadIdx.x;
    if (i < RANGES * NSUB) cnt[i] = 0u;
}

// Phase 1: one visit per edge. Gather once, wave-compact 4B records into
// per-(range, sub-bucket) regions with one atomic reservation per wave-range.
__global__ void __launch_bounds__(P1_THREADS) bucket_kernel(
        const float* __restrict__ x, const int* __restrict__ ei,
        const float* __restrict__ w, unsigned* __restrict__ buckets,
        unsigned* __restrict__ cnt) {
    const int lane   = threadIdx.x & 63;
    const int g      = blockIdx.x & (NSUB - 1);
    const int gwave  = blockIdx.x * (P1_THREADS / 64) + (threadIdx.x >> 6);
    const int nwaves = P1_BLOCKS * (P1_THREADS / 64);
    const int ngroups = N_EDGES / 256;  // 25000, one group = 256 edges per wave
    const unsigned long long lt = (lane == 63) ? ~0ull >> 1 : (1ull << lane) - 1;

    const int* srcp = ei;
    const int* dstp = ei + N_EDGES;

    for (int grp = gwave; grp < ngroups; grp += nwaves) {
        const int e0 = grp * 256 + lane * 4;
        int4   s4 = *reinterpret_cast<const int4*>(srcp + e0);
        int4   d4 = *reinterpret_cast<const int4*>(dstp + e0);
        float4 w4 = *reinterpret_cast<const float4*>(w + e0);

        // exactly one gather per edge
        float x0 = x[d4.x], x1 = x[d4.y], x2 = x[d4.z], x3 = x[d4.w];
        int s[4] = { s4.x, s4.y, s4.z, s4.w };
        unsigned mb[4] = { bf16_rne(w4.x * x0), bf16_rne(w4.y * x1),
                           bf16_rne(w4.z * x2), bf16_rne(w4.w * x3) };

        #pragma unroll
        for (int r = 0; r < RANGES; ++r) {
            const int lo = r * RANGE_S;
            unsigned long long bm[4];
            int c = 0;
            #pragma unroll
            for (int sl = 0; sl < 4; ++sl) {
                bm[sl] = __ballot((unsigned)(s[sl] - lo) < RANGE_S);
                c += __popcll(bm[sl]);
            }
            unsigned base = 0;
            if (lane == 0 && c) base = atomicAdd(&cnt[r * NSUB + g], (unsigned)c);
            base = __shfl(base, 0);
            if (base + (unsigned)c > CAP) continue;  // safety clamp (sized to never hit)
            unsigned* bptr = buckets + (size_t)(r * NSUB + g) * CAP;
            unsigned run = base;
            #pragma unroll
            for (int sl = 0; sl < 4; ++sl) {
                if ((unsigned)(s[sl] - lo) < RANGE_S) {
                    unsigned pos = run + (unsigned)__popcll(bm[sl] & lt);
                    bptr[pos] = ((unsigned)(s[sl] - lo) << 16) | mb[sl];
                }
                run += (unsigned)__popcll(bm[sl]);
            }
        }
    }
}

// Phase 2: each block bins its sub-buckets' records into LDS (all lanes useful).
__global__ void __launch_bounds__(1024) bin_kernel(
        const unsigned* __restrict__ buckets, const unsigned* __restrict__ cnt,
        float* __restrict__ partial, int nb2) {
    __shared__ float bins[RANGE_S];
    const int r = blockIdx.x / nb2;
    const int b = blockIdx.x - r * nb2;
    for (int i = threadIdx.x; i < RANGE_S; i += 1024) bins[i] = 0.0f;
    __syncthreads();
    const int spb = NSUB / nb2;
    for (int j = 0; j < spb; ++j) {
        const int g = b * spb + j;
        int n = (int)cnt[r * NSUB + g];
        if (n > CAP) n = CAP;
        const unsigned* bp = buckets + (size_t)(r * NSUB + g) * CAP;
        for (int i = threadIdx.x; i < n; i += 1024) {
            unsigned rec = bp[i];
            float msg = __uint_as_float((rec & 0xFFFFu) << 16);
            atomicAdd(&bins[rec >> 16], msg);
        }
    }
    __syncthreads();
    float* outp = partial + (size_t)blockIdx.x * RANGE_S;
    for (int i = threadIdx.x; i < RANGE_S; i += 1024) outp[i] = bins[i];
}

__global__ void reduce2_kernel(const float* __restrict__ partial,
                               float* __restrict__ out, int nb2) {
    int i = blockIdx.x * blockDim.x + threadIdx.x;
    int n0 = i * 4;
    if (n0 >= N_NODES) return;
    int r = n0 / RANGE_S;
    int s = n0 - r * RANGE_S;
    float4 acc = make_float4(0.f,0.f,0.f,0.f);
    for (int b = 0; b < nb2; ++b) {
        float4 v = *reinterpret_cast<const float4*>(partial + (size_t)(r * nb2 + b) * RANGE_S + s);
        acc.x += v.x; acc.y += v.y; acc.z += v.z; acc.w += v.w;
    }
    *reinterpret_cast<float4*>(out + n0) = acc;
}

extern "C" void kernel_launch(void* const* d_in, const int* in_sizes, int n_in,
                              void* d_out, int out_size, void* d_ws, size_t ws_size,
                              hipStream_t stream) {
    const float* x   = (const float*)d_in[0];
    const int*   ei  = (const int*)d_in[1];
    const float* w   = (const float*)d_in[2];
    float*       out = (float*)d_out;

    const size_t bucket_bytes = (size_t)RANGES * NSUB * CAP * 4;   // ~27.8 MB
    const size_t cnt_bytes    = (size_t)RANGES * NSUB * 4;         // 2 KB

    int nb2 = 0;
    for (int cand = 32; cand >= 8; cand >>= 1) {
        size_t partial_bytes = (size_t)RANGES * cand * RANGE_S * 4;
        if (ws_size >= bucket_bytes + partial_bytes + cnt_bytes) { nb2 = cand; break; }
    }

    if (nb2 > 0) {
        // layout: [buckets][partials][cnt]
        unsigned* buckets = (unsigned*)d_ws;
        float*    partial = (float*)((char*)d_ws + bucket_bytes);
        unsigned* cnt     = (unsigned*)((char*)d_ws + bucket_bytes +
                                        (size_t)RANGES * nb2 * RANGE_S * 4);
        zero_cnt_kernel<<<1, RANGES * NSUB, 0, stream>>>(cnt);
        bucket_kernel<<<P1_BLOCKS, P1_THREADS, 0, stream>>>(x, ei, w, buckets, cnt);
        bin_kernel<<<RANGES * nb2, 1024, 0, stream>>>(buckets, cnt, partial, nb2);
        reduce2_kernel<<<(N_NODES / 4 + 255) / 256, 256, 0, stream>>>(partial, out, nb2);
    } else if (ws_size >= (size_t)RANGES * NB * RANGE_S * sizeof(float)) {
        float* partial = (float*)d_ws;
        scatter_range_kernel<<<RANGES * NB, BLK, 0, stream>>>(x, ei, w, partial);
        reduce_range_kernel<<<(N_NODES / 4 + 255) / 256, 256, 0, stream>>>(partial, out);
    } else {
        zero_out_kernel<<<(N_NODES + 255) / 256, 256, 0, stream>>>(out, N_NODES);
        scatter_direct_kernel<<<(N_EDGES / 4 + 255) / 256, 256, 0, stream>>>(x, ei, w, out);
    }
}

// Round 7
// 79.234 us; speedup vs baseline: 2.1430x; 2.1430x over previous
//
#include <hip/hip_runtime.h>

#define N_NODES 100000
#define N_EDGES 6400000
#define RANGES 4
#define RANGE_S 25000   // nodes per range; RANGES * RANGE_S == N_NODES
#define NB 64           // chunks per range -> 256 bin blocks
#define BLK 1024

// ============ fallback path A: direct device atomics ============
__global__ void zero_out_kernel(float* __restrict__ out, int n) {
    int i = blockIdx.x * blockDim.x + threadIdx.x;
    if (i < n) out[i] = 0.0f;
}

__global__ void __launch_bounds__(256) scatter_direct_kernel(
        const float* __restrict__ x, const int* __restrict__ ei,
        const float* __restrict__ w, float* __restrict__ out) {
    int t = blockIdx.x * blockDim.x + threadIdx.x;
    int e0 = t * 4;
    if (e0 >= N_EDGES) return;
    int4   s4 = *reinterpret_cast<const int4*>(ei + e0);
    int4   d4 = *reinterpret_cast<const int4*>(ei + N_EDGES + e0);
    float4 w4 = *reinterpret_cast<const float4*>(w + e0);
    atomicAdd(&out[s4.x], w4.x * x[d4.x]);
    atomicAdd(&out[s4.y], w4.y * x[d4.y]);
    atomicAdd(&out[s4.z], w4.z * x[d4.z]);
    atomicAdd(&out[s4.w], w4.w * x[d4.w]);
}

// ============ fallback path B: R5 one-pass range kernel ============
__global__ void __launch_bounds__(BLK) scatter_range_kernel(
        const float* __restrict__ x, const int* __restrict__ ei,
        const float* __restrict__ w, float* __restrict__ partial) {
    __shared__ float bins[RANGE_S];
    const int r = blockIdx.x & (RANGES - 1);
    const int c = blockIdx.x >> 2;
    for (int i = threadIdx.x; i < RANGE_S; i += BLK) bins[i] = 0.0f;
    __syncthreads();
    const int chunk = N_EDGES / NB;
    const int base  = c * chunk;
    const int end   = base + chunk;
    const int lo    = r * RANGE_S;
    for (int e = base + (int)threadIdx.x * 8; e < end; e += BLK * 8) {
        int4   sa = *reinterpret_cast<const int4*>(ei + e);
        int4   sb = *reinterpret_cast<const int4*>(ei + e + 4);
        int4   da = *reinterpret_cast<const int4*>(ei + N_EDGES + e);
        int4   db = *reinterpret_cast<const int4*>(ei + N_EDGES + e + 4);
        float4 wa = *reinterpret_cast<const float4*>(w + e);
        float4 wb = *reinterpret_cast<const float4*>(w + e + 4);
        unsigned a[8] = {(unsigned)(sa.x-lo),(unsigned)(sa.y-lo),(unsigned)(sa.z-lo),(unsigned)(sa.w-lo),
                         (unsigned)(sb.x-lo),(unsigned)(sb.y-lo),(unsigned)(sb.z-lo),(unsigned)(sb.w-lo)};
        int d[8] = {da.x,da.y,da.z,da.w,db.x,db.y,db.z,db.w};
        float ww[8] = {wa.x,wa.y,wa.z,wa.w,wb.x,wb.y,wb.z,wb.w};
        float xv[8];
        #pragma unroll
        for (int k = 0; k < 8; ++k) { int gi = (a[k] < RANGE_S) ? d[k] : 0; xv[k] = x[gi]; }
        #pragma unroll
        for (int k = 0; k < 8; ++k) asm volatile("" : "+v"(xv[k]));
        #pragma unroll
        for (int k = 0; k < 8; ++k) if (a[k] < RANGE_S) atomicAdd(&bins[a[k]], ww[k] * xv[k]);
    }
    __syncthreads();
    float* outp = partial + (size_t)(r * NB + c) * RANGE_S;
    for (int i = threadIdx.x; i < RANGE_S; i += BLK) outp[i] = bins[i];
}

// ============ main path: transform (one gather/edge) + bin + reduce ============
__device__ __forceinline__ unsigned bf16_rne(float f) {
    unsigned b = __float_as_uint(f);
    b += 0x7FFFu + ((b >> 16) & 1u);
    return b >> 16;
}

// Phase 1: msg[e] = bf16(w[e] * x[dst[e]]). Linear coalesced writes, no atomics.
__global__ void __launch_bounds__(256) transform_kernel(
        const float* __restrict__ x, const int* __restrict__ ei,
        const float* __restrict__ w, unsigned short* __restrict__ msg) {
    int t = blockIdx.x * blockDim.x + threadIdx.x;
    int e0 = t * 8;
    if (e0 >= N_EDGES) return;
    const int* dstp = ei + N_EDGES;
    int4   da = *reinterpret_cast<const int4*>(dstp + e0);
    int4   db = *reinterpret_cast<const int4*>(dstp + e0 + 4);
    float4 wa = *reinterpret_cast<const float4*>(w + e0);
    float4 wb = *reinterpret_cast<const float4*>(w + e0 + 4);

    float xv[8] = { x[da.x], x[da.y], x[da.z], x[da.w],
                    x[db.x], x[db.y], x[db.z], x[db.w] };
    float ww[8] = { wa.x, wa.y, wa.z, wa.w, wb.x, wb.y, wb.z, wb.w };

    uint4 o;
    o.x = bf16_rne(ww[0] * xv[0]) | (bf16_rne(ww[1] * xv[1]) << 16);
    o.y = bf16_rne(ww[2] * xv[2]) | (bf16_rne(ww[3] * xv[3]) << 16);
    o.z = bf16_rne(ww[4] * xv[4]) | (bf16_rne(ww[5] * xv[5]) << 16);
    o.w = bf16_rne(ww[6] * xv[6]) | (bf16_rne(ww[7] * xv[7]) << 16);
    *reinterpret_cast<uint4*>(msg + e0) = o;   // e0 % 8 == 0 -> 16B aligned
}

// Phase 2: R5's bin structure, but stream is 6B/edge (src + bf16 msg), no gathers.
__global__ void __launch_bounds__(BLK) bin_kernel(
        const int* __restrict__ ei, const unsigned short* __restrict__ msg,
        float* __restrict__ partial) {
    __shared__ float bins[RANGE_S];
    const int r = blockIdx.x & (RANGES - 1);
    const int c = blockIdx.x >> 2;
    for (int i = threadIdx.x; i < RANGE_S; i += BLK) bins[i] = 0.0f;
    __syncthreads();

    const int chunk = N_EDGES / NB;   // 100000, % 8 == 0
    const int base  = c * chunk;
    const int end   = base + chunk;
    const int lo    = r * RANGE_S;

    for (int e = base + (int)threadIdx.x * 8; e < end; e += BLK * 8) {
        int4 sa = *reinterpret_cast<const int4*>(ei + e);
        int4 sb = *reinterpret_cast<const int4*>(ei + e + 4);
        uint4 mm = *reinterpret_cast<const uint4*>(msg + e);

        unsigned a[8] = {(unsigned)(sa.x-lo),(unsigned)(sa.y-lo),(unsigned)(sa.z-lo),(unsigned)(sa.w-lo),
                         (unsigned)(sb.x-lo),(unsigned)(sb.y-lo),(unsigned)(sb.z-lo),(unsigned)(sb.w-lo)};
        float f[8] = {
            __uint_as_float((mm.x & 0xFFFFu) << 16), __uint_as_float(mm.x & 0xFFFF0000u),
            __uint_as_float((mm.y & 0xFFFFu) << 16), __uint_as_float(mm.y & 0xFFFF0000u),
            __uint_as_float((mm.z & 0xFFFFu) << 16), __uint_as_float(mm.z & 0xFFFF0000u),
            __uint_as_float((mm.w & 0xFFFFu) << 16), __uint_as_float(mm.w & 0xFFFF0000u)
        };
        #pragma unroll
        for (int k = 0; k < 8; ++k) {
            if (a[k] < RANGE_S) atomicAdd(&bins[a[k]], f[k]);   // ds_add_f32
        }
    }
    __syncthreads();
    float* outp = partial + (size_t)(r * NB + c) * RANGE_S;
    for (int i = threadIdx.x; i < RANGE_S; i += BLK) outp[i] = bins[i];
}

__global__ void reduce_range_kernel(const float* __restrict__ partial, float* __restrict__ out) {
    int i = blockIdx.x * blockDim.x + threadIdx.x;
    int n0 = i * 4;
    if (n0 >= N_NODES) return;
    int r = n0 / RANGE_S;
    int s = n0 - r * RANGE_S;
    const float* base = partial + (size_t)(r * NB) * RANGE_S + s;
    float4 acc = make_float4(0.f,0.f,0.f,0.f);
    for (int j = 0; j < NB; ++j) {
        float4 v = *reinterpret_cast<const float4*>(base + (size_t)j * RANGE_S);
        acc.x += v.x; acc.y += v.y; acc.z += v.z; acc.w += v.w;
    }
    *reinterpret_cast<float4*>(out + n0) = acc;
}

extern "C" void kernel_launch(void* const* d_in, const int* in_sizes, int n_in,
                              void* d_out, int out_size, void* d_ws, size_t ws_size,
                              hipStream_t stream) {
    const float* x   = (const float*)d_in[0];
    const int*   ei  = (const int*)d_in[1];
    const float* w   = (const float*)d_in[2];
    float*       out = (float*)d_out;

    const size_t msg_bytes     = (size_t)N_EDGES * 2;                       // 12.8 MB
    const size_t partial_bytes = (size_t)RANGES * NB * RANGE_S * 4;         // 25.6 MB

    if (ws_size >= msg_bytes + partial_bytes) {
        unsigned short* msg = (unsigned short*)d_ws;
        float* partial = (float*)((char*)d_ws + msg_bytes);
        transform_kernel<<<N_EDGES / 8 / 256, 256, 0, stream>>>(x, ei, w, msg);
        bin_kernel<<<RANGES * NB, BLK, 0, stream>>>(ei, msg, partial);
        reduce_range_kernel<<<(N_NODES / 4 + 255) / 256, 256, 0, stream>>>(partial, out);
    } else if (ws_size >= partial_bytes) {
        float* partial = (float*)d_ws;
        scatter_range_kernel<<<RANGES * NB, BLK, 0, stream>>>(x, ei, w, partial);
        reduce_range_kernel<<<(N_NODES / 4 + 255) / 256, 256, 0, stream>>>(partial, out);
    } else {
        zero_out_kernel<<<(N_NODES + 255) / 256, 256, 0, stream>>>(out, N_NODES);
        scatter_direct_kernel<<<(N_EDGES / 4 + 255) / 256, 256, 0, stream>>>(x, ei, w, out);
    }
}

// Round 8
// 78.110 us; speedup vs baseline: 2.1738x; 1.0144x over previous
//
#include <hip/hip_runtime.h>

#define N_NODES 100000
#define N_EDGES 6400000
#define RANGES 8
#define RANGE_S 12500   // nodes per range; RANGES * RANGE_S == N_NODES
#define NB 64           // chunks; chunk = 100000 edges
#define BLK 1024

// ============ fallback path A: direct device atomics ============
__global__ void zero_out_kernel(float* __restrict__ out, int n) {
    int i = blockIdx.x * blockDim.x + threadIdx.x;
    if (i < n) out[i] = 0.0f;
}

__global__ void __launch_bounds__(256) scatter_direct_kernel(
        const float* __restrict__ x, const int* __restrict__ ei,
        const float* __restrict__ w, float* __restrict__ out) {
    int t = blockIdx.x * blockDim.x + threadIdx.x;
    int e0 = t * 4;
    if (e0 >= N_EDGES) return;
    int4   s4 = *reinterpret_cast<const int4*>(ei + e0);
    int4   d4 = *reinterpret_cast<const int4*>(ei + N_EDGES + e0);
    float4 w4 = *reinterpret_cast<const float4*>(w + e0);
    atomicAdd(&out[s4.x], w4.x * x[d4.x]);
    atomicAdd(&out[s4.y], w4.y * x[d4.y]);
    atomicAdd(&out[s4.z], w4.z * x[d4.z]);
    atomicAdd(&out[s4.w], w4.w * x[d4.w]);
}

// ============ main path: transform (one gather/edge) + bin + reduce ============
__device__ __forceinline__ unsigned bf16_rne(float f) {
    unsigned b = __float_as_uint(f);
    b += 0x7FFFu + ((b >> 16) & 1u);
    return b >> 16;
}

// Phase 1: msg[e] = bf16(w[e] * x[dst[e]]). Linear coalesced writes, no atomics.
__global__ void __launch_bounds__(256) transform_kernel(
        const float* __restrict__ x, const int* __restrict__ ei,
        const float* __restrict__ w, unsigned short* __restrict__ msg) {
    int t = blockIdx.x * blockDim.x + threadIdx.x;
    int e0 = t * 8;
    if (e0 >= N_EDGES) return;
    const int* dstp = ei + N_EDGES;
    int4   da = *reinterpret_cast<const int4*>(dstp + e0);
    int4   db = *reinterpret_cast<const int4*>(dstp + e0 + 4);
    float4 wa = *reinterpret_cast<const float4*>(w + e0);
    float4 wb = *reinterpret_cast<const float4*>(w + e0 + 4);

    float xv[8] = { x[da.x], x[da.y], x[da.z], x[da.w],
                    x[db.x], x[db.y], x[db.z], x[db.w] };
    float ww[8] = { wa.x, wa.y, wa.z, wa.w, wb.x, wb.y, wb.z, wb.w };

    uint4 o;
    o.x = bf16_rne(ww[0] * xv[0]) | (bf16_rne(ww[1] * xv[1]) << 16);
    o.y = bf16_rne(ww[2] * xv[2]) | (bf16_rne(ww[3] * xv[3]) << 16);
    o.z = bf16_rne(ww[4] * xv[4]) | (bf16_rne(ww[5] * xv[5]) << 16);
    o.w = bf16_rne(ww[6] * xv[6]) | (bf16_rne(ww[7] * xv[7]) << 16);
    *reinterpret_cast<uint4*>(msg + e0) = o;
}

// Phase 2: 8 ranges x 50KB bins -> 2 blocks/CU (32 waves/CU).
// XCD swizzle: all 8 range-siblings of a chunk land on the same XCD
// (assumes round-robin b%8 dispatch; if not, it's a harmless no-op for perf).
__global__ void __launch_bounds__(BLK) bin_kernel(
        const int* __restrict__ ei, const unsigned short* __restrict__ msg,
        float* __restrict__ partial) {
    __shared__ float bins[RANGE_S];   // 50 KB
    const int b    = blockIdx.x;      // 0..511
    const int xcd  = b & 7;
    const int slot = b >> 3;          // 0..63
    const int r    = slot & 7;        // range
    const int c    = (slot >> 3) * 8 + xcd;  // chunk 0..63

    for (int i = threadIdx.x; i < RANGE_S; i += BLK) bins[i] = 0.0f;
    __syncthreads();

    const int chunk = N_EDGES / NB;   // 100000, % 8 == 0
    const int base  = c * chunk;
    const int end   = base + chunk;
    const int lo    = r * RANGE_S;

    for (int e = base + (int)threadIdx.x * 8; e < end; e += BLK * 8) {
        int4 sa = *reinterpret_cast<const int4*>(ei + e);
        int4 sb = *reinterpret_cast<const int4*>(ei + e + 4);
        uint4 mm = *reinterpret_cast<const uint4*>(msg + e);

        unsigned a[8] = {(unsigned)(sa.x-lo),(unsigned)(sa.y-lo),(unsigned)(sa.z-lo),(unsigned)(sa.w-lo),
                         (unsigned)(sb.x-lo),(unsigned)(sb.y-lo),(unsigned)(sb.z-lo),(unsigned)(sb.w-lo)};
        float f[8] = {
            __uint_as_float((mm.x & 0xFFFFu) << 16), __uint_as_float(mm.x & 0xFFFF0000u),
            __uint_as_float((mm.y & 0xFFFFu) << 16), __uint_as_float(mm.y & 0xFFFF0000u),
            __uint_as_float((mm.z & 0xFFFFu) << 16), __uint_as_float(mm.z & 0xFFFF0000u),
            __uint_as_float((mm.w & 0xFFFFu) << 16), __uint_as_float(mm.w & 0xFFFF0000u)
        };
        #pragma unroll
        for (int k = 0; k < 8; ++k) {
            if (a[k] < RANGE_S) atomicAdd(&bins[a[k]], f[k]);   // ds_add_f32
        }
    }
    __syncthreads();
    float* outp = partial + (size_t)(r * NB + c) * RANGE_S;
    for (int i = threadIdx.x; i < RANGE_S; i += BLK) outp[i] = bins[i];
}

__global__ void reduce_range_kernel(const float* __restrict__ partial, float* __restrict__ out) {
    int i = blockIdx.x * blockDim.x + threadIdx.x;
    int n0 = i * 4;
    if (n0 >= N_NODES) return;
    int r = n0 / RANGE_S;
    int s = n0 - r * RANGE_S;          // RANGE_S % 4 == 0 -> no straddle
    const float* base = partial + (size_t)(r * NB) * RANGE_S + s;
    float4 acc = make_float4(0.f,0.f,0.f,0.f);
    for (int j = 0; j < NB; ++j) {
        float4 v = *reinterpret_cast<const float4*>(base + (size_t)j * RANGE_S);
        acc.x += v.x; acc.y += v.y; acc.z += v.z; acc.w += v.w;
    }
    *reinterpret_cast<float4*>(out + n0) = acc;
}

extern "C" void kernel_launch(void* const* d_in, const int* in_sizes, int n_in,
                              void* d_out, int out_size, void* d_ws, size_t ws_size,
                              hipStream_t stream) {
    const float* x   = (const float*)d_in[0];
    const int*   ei  = (const int*)d_in[1];
    const float* w   = (const float*)d_in[2];
    float*       out = (float*)d_out;

    const size_t msg_bytes     = (size_t)N_EDGES * 2;                 // 12.8 MB
    const size_t partial_bytes = (size_t)RANGES * NB * RANGE_S * 4;   // 25.6 MB

    if (ws_size >= msg_bytes + partial_bytes) {
        unsigned short* msg = (unsigned short*)d_ws;
        float* partial = (float*)((char*)d_ws + msg_bytes);
        transform_kernel<<<N_EDGES / 8 / 256, 256, 0, stream>>>(x, ei, w, msg);
        bin_kernel<<<RANGES * NB, BLK, 0, stream>>>(ei, msg, partial);
        reduce_range_kernel<<<(N_NODES / 4 + 255) / 256, 256, 0, stream>>>(partial, out);
    } else {
        zero_out_kernel<<<(N_NODES + 255) / 256, 256, 0, stream>>>(out, N_NODES);
        scatter_direct_kernel<<<(N_EDGES / 4 + 255) / 256, 256, 0, stream>>>(x, ei, w, out);
    }
}

// Round 9
// 59.641 us; speedup vs baseline: 2.8470x; 1.3097x over previous
//
#include <hip/hip_runtime.h>

#define N_NODES 100000
#define N_EDGES 6400000
#define RANGES 8
#define RANGE_S 12500   // nodes per range; RANGES * RANGE_S == N_NODES
#define NB 64           // chunks; chunk = 100000 edges
#define BLK 1024
#define FIX_SCALE 1048576.0f        // 2^20
#define FIX_INV   (1.0f / 1048576.0f)

// ============ fallback path A: direct device atomics ============
__global__ void zero_out_kernel(float* __restrict__ out, int n) {
    int i = blockIdx.x * blockDim.x + threadIdx.x;
    if (i < n) out[i] = 0.0f;
}

__global__ void __launch_bounds__(256) scatter_direct_kernel(
        const float* __restrict__ x, const int* __restrict__ ei,
        const float* __restrict__ w, float* __restrict__ out) {
    int t = blockIdx.x * blockDim.x + threadIdx.x;
    int e0 = t * 4;
    if (e0 >= N_EDGES) return;
    int4   s4 = *reinterpret_cast<const int4*>(ei + e0);
    int4   d4 = *reinterpret_cast<const int4*>(ei + N_EDGES + e0);
    float4 w4 = *reinterpret_cast<const float4*>(w + e0);
    atomicAdd(&out[s4.x], w4.x * x[d4.x]);
    atomicAdd(&out[s4.y], w4.y * x[d4.y]);
    atomicAdd(&out[s4.z], w4.z * x[d4.z]);
    atomicAdd(&out[s4.w], w4.w * x[d4.w]);
}

// ============ main path: transform + int-fixed-point bin + exact reduce ============
__device__ __forceinline__ unsigned bf16_rne(float f) {
    unsigned b = __float_as_uint(f);
    b += 0x7FFFu + ((b >> 16) & 1u);
    return b >> 16;
}

// Phase 1: msg[e] = bf16(w[e] * x[dst[e]]). Linear coalesced writes, no atomics.
__global__ void __launch_bounds__(256) transform_kernel(
        const float* __restrict__ x, const int* __restrict__ ei,
        const float* __restrict__ w, unsigned short* __restrict__ msg) {
    int t = blockIdx.x * blockDim.x + threadIdx.x;
    int e0 = t * 8;
    if (e0 >= N_EDGES) return;
    const int* dstp = ei + N_EDGES;
    int4   da = *reinterpret_cast<const int4*>(dstp + e0);
    int4   db = *reinterpret_cast<const int4*>(dstp + e0 + 4);
    float4 wa = *reinterpret_cast<const float4*>(w + e0);
    float4 wb = *reinterpret_cast<const float4*>(w + e0 + 4);

    float xv[8] = { x[da.x], x[da.y], x[da.z], x[da.w],
                    x[db.x], x[db.y], x[db.z], x[db.w] };
    float ww[8] = { wa.x, wa.y, wa.z, wa.w, wb.x, wb.y, wb.z, wb.w };

    uint4 o;
    o.x = bf16_rne(ww[0] * xv[0]) | (bf16_rne(ww[1] * xv[1]) << 16);
    o.y = bf16_rne(ww[2] * xv[2]) | (bf16_rne(ww[3] * xv[3]) << 16);
    o.z = bf16_rne(ww[4] * xv[4]) | (bf16_rne(ww[5] * xv[5]) << 16);
    o.w = bf16_rne(ww[6] * xv[6]) | (bf16_rne(ww[7] * xv[7]) << 16);
    *reinterpret_cast<uint4*>(msg + e0) = o;
}

// Phase 2: identical structure to R8, but bins are int32 fixed-point (2^20).
// A/B test: if integer LDS atomics are bank-parallel (vs ~4cy/lane for ds_add_f32),
// this kernel drops from 42us to ~10-20us with no other change.
__global__ void __launch_bounds__(BLK) bin_kernel(
        const int* __restrict__ ei, const unsigned short* __restrict__ msg,
        int* __restrict__ partial) {
    __shared__ int bins[RANGE_S];   // 50 KB
    const int b    = blockIdx.x;    // 0..511
    const int xcd  = b & 7;
    const int slot = b >> 3;        // 0..63
    const int r    = slot & 7;      // range
    const int c    = (slot >> 3) * 8 + xcd;  // chunk 0..63 (siblings share XCD)

    for (int i = threadIdx.x; i < RANGE_S; i += BLK) bins[i] = 0;
    __syncthreads();

    const int chunk = N_EDGES / NB;   // 100000, % 8 == 0
    const int base  = c * chunk;
    const int end   = base + chunk;
    const int lo    = r * RANGE_S;

    for (int e = base + (int)threadIdx.x * 8; e < end; e += BLK * 8) {
        int4 sa = *reinterpret_cast<const int4*>(ei + e);
        int4 sb = *reinterpret_cast<const int4*>(ei + e + 4);
        uint4 mm = *reinterpret_cast<const uint4*>(msg + e);

        unsigned a[8] = {(unsigned)(sa.x-lo),(unsigned)(sa.y-lo),(unsigned)(sa.z-lo),(unsigned)(sa.w-lo),
                         (unsigned)(sb.x-lo),(unsigned)(sb.y-lo),(unsigned)(sb.z-lo),(unsigned)(sb.w-lo)};
        float f[8] = {
            __uint_as_float((mm.x & 0xFFFFu) << 16), __uint_as_float(mm.x & 0xFFFF0000u),
            __uint_as_float((mm.y & 0xFFFFu) << 16), __uint_as_float(mm.y & 0xFFFF0000u),
            __uint_as_float((mm.z & 0xFFFFu) << 16), __uint_as_float(mm.z & 0xFFFF0000u),
            __uint_as_float((mm.w & 0xFFFFu) << 16), __uint_as_float(mm.w & 0xFFFF0000u)
        };
        int mi[8];
        #pragma unroll
        for (int k = 0; k < 8; ++k) mi[k] = (int)__builtin_rintf(f[k] * FIX_SCALE);
        #pragma unroll
        for (int k = 0; k < 8; ++k) {
            if (a[k] < RANGE_S) atomicAdd(&bins[a[k]], mi[k]);   // integer LDS atomic
        }
    }
    __syncthreads();
    int* outp = partial + (size_t)(r * NB + c) * RANGE_S;
    for (int i = threadIdx.x; i < RANGE_S; i += BLK) outp[i] = bins[i];
}

// Reduce: exact integer sum of 64 chunk-partials, single float convert.
__global__ void reduce_range_kernel(const int* __restrict__ partial, float* __restrict__ out) {
    int i = blockIdx.x * blockDim.x + threadIdx.x;
    int n0 = i * 4;
    if (n0 >= N_NODES) return;
    int r = n0 / RANGE_S;
    int s = n0 - r * RANGE_S;          // RANGE_S % 4 == 0 -> no straddle
    const int* base = partial + (size_t)(r * NB) * RANGE_S + s;
    int4 acc = make_int4(0, 0, 0, 0);
    for (int j = 0; j < NB; ++j) {
        int4 v = *reinterpret_cast<const int4*>(base + (size_t)j * RANGE_S);
        acc.x += v.x; acc.y += v.y; acc.z += v.z; acc.w += v.w;
    }
    float4 o = make_float4((float)acc.x * FIX_INV, (float)acc.y * FIX_INV,
                           (float)acc.z * FIX_INV, (float)acc.w * FIX_INV);
    *reinterpret_cast<float4*>(out + n0) = o;
}

extern "C" void kernel_launch(void* const* d_in, const int* in_sizes, int n_in,
                              void* d_out, int out_size, void* d_ws, size_t ws_size,
                              hipStream_t stream) {
    const float* x   = (const float*)d_in[0];
    const int*   ei  = (const int*)d_in[1];
    const float* w   = (const float*)d_in[2];
    float*       out = (float*)d_out;

    const size_t msg_bytes     = (size_t)N_EDGES * 2;                 // 12.8 MB
    const size_t partial_bytes = (size_t)RANGES * NB * RANGE_S * 4;   // 25.6 MB

    if (ws_size >= msg_bytes + partial_bytes) {
        unsigned short* msg = (unsigned short*)d_ws;
        int* partial = (int*)((char*)d_ws + msg_bytes);
        transform_kernel<<<N_EDGES / 8 / 256, 256, 0, stream>>>(x, ei, w, msg);
        bin_kernel<<<RANGES * NB, BLK, 0, stream>>>(ei, msg, partial);
        reduce_range_kernel<<<(N_NODES / 4 + 255) / 256, 256, 0, stream>>>(partial, out);
    } else {
        zero_out_kernel<<<(N_NODES + 255) / 256, 256, 0, stream>>>(out, N_NODES);
        scatter_direct_kernel<<<(N_EDGES / 4 + 255) / 256, 256, 0, stream>>>(x, ei, w, out);
    }
}